// Round 9
// baseline (327.406 us; speedup 1.0000x reference)
//
#include <hip/hip_runtime.h>
#include <hip/hip_fp16.h>

// VQ codebook quantization, MI355X.
//   prep:   fp32->bf16 fragment repack + norms + all zero-inits (no memsets).
//   passA:  barrier-free LDS-free bf16 MFMA -> per-(row,16-code-window) minima.
//   passB1: stream tm, per-row min+EPS ballot -> (row,win) pair queue.
//   passB2: wave per 2 pairs (pipelined): exact fp32 rescore, 64-bit atomicMin
//           winner (dist_bits<<32|k: exact reference value + lowest-k ties).
//   passB3: wave per 8 rows: gather quantized, indices, counts, loss partials.
//   final:  perplexity + losses.
// B=8192, d_latent=512, ncb=2, K=8192, d_sub=256.

#define KCODES 8192
#define DSUB   256
#define BROWS  8192
#define NROWS  16384
#define NWIN   512

#define QUANT_N  (BROWS * 512)
#define IDX_OFF  QUANT_N
#define LOSS_OFF (QUANT_N + NROWS)

// ws layout (bytes)
#define WS_ESQ     0          // 16384 f32
#define WS_ZSQ     65536      // 16384 f32
#define WS_COUNTS  131072     // 16384 i32   (zeroed in prep)
#define WS_WINNER  196608     // 16384 u64   (0xFF.. in prep)
#define WS_LOSSARR 327680     // 2048 f32    (every slot written by passB3)
#define WS_QTAIL   335872     // 1 u32       (zeroed in prep)
#define WS_ZBF     1048576    // [2][8192][256] bf16 = 8 MB, fragment layout
#define WS_QUEUE   1048576    // u32 pairs — REUSES zbf (dead after passA)
#define QCAP       2000000
#define WS_EBF     9437184    // [2][8192][256] bf16 = 8 MB, fragment layout
#define WS_TM      17825792   // [2][8192][512] fp16 = 16 MB

#define EPS 2.5e-4f

// Fragment layout (elements, per codebook): row r, element k ->
//   (r>>4)*4096 + (k>>5)*512 + ((k>>3)&3)*128 + (r&15)*8 + (k&7)

typedef __attribute__((ext_vector_type(8))) short short8;
typedef __attribute__((ext_vector_type(8))) unsigned short ushort8v;
typedef __attribute__((ext_vector_type(4))) float floatx4;

__device__ inline unsigned short f2bf(float f) {
  unsigned u = __float_as_uint(f);
  return (unsigned short)((u + 0x7FFFu + ((u >> 16) & 1u)) >> 16);
}

// ------------------------------------------------------------ prep kernel
__global__ void prep_kernel(const float* __restrict__ z, const float* __restrict__ e,
                            float* __restrict__ e_sq, float* __restrict__ z_sq,
                            unsigned short* __restrict__ zbf, unsigned short* __restrict__ ebf,
                            int* __restrict__ counts, unsigned long long* __restrict__ winner,
                            unsigned* __restrict__ qtail) {
  int t = blockIdx.x * 256 + threadIdx.x;
  if (t < 16384) { counts[t] = 0; winner[t] = ~0ull; }
  if (t == 16384) *qtail = 0;

  int gw  = blockIdx.x * 4 + (threadIdx.x >> 6);  // 0..4095
  int l   = threadIdx.x & 63;
  int sub = l >> 5;
  int l32 = l & 31;
  for (int i = 0; i < 4; ++i) {
    int row = i * 8192 + gw * 2 + sub;            // 0..32767 (i<2: emb, else z)
    const float* src;
    unsigned short* dst;
    int r;
    float* sq;
    int sqi;
    if (row < NROWS) {
      src = e + (size_t)row * DSUB;
      dst = ebf; r = row; sq = e_sq; sqi = row;
    } else {
      int rz = row - NROWS;
      int n = rz & 1, b = rz >> 1;
      src = z + (size_t)rz * DSUB;
      dst = zbf + (size_t)n * 2097152; r = b; sq = z_sq; sqi = rz;
    }
    float4 v0 = ((const float4*)src)[2 * l32];
    float4 v1 = ((const float4*)src)[2 * l32 + 1];
    ushort8v o;
    o[0] = f2bf(v0.x); o[1] = f2bf(v0.y); o[2] = f2bf(v0.z); o[3] = f2bf(v0.w);
    o[4] = f2bf(v1.x); o[5] = f2bf(v1.y); o[6] = f2bf(v1.z); o[7] = f2bf(v1.w);
    size_t off = (size_t)(r >> 4) * 4096 + (l32 >> 2) * 512 + (l32 & 3) * 128 + (r & 15) * 8;
    *(ushort8v*)(dst + off) = o;
    float s = v0.x * v0.x + v0.y * v0.y + v0.z * v0.z + v0.w * v0.w
            + v1.x * v1.x + v1.y * v1.y + v1.z * v1.z + v1.w * v1.w;
    #pragma unroll
    for (int off2 = 16; off2; off2 >>= 1) s += __shfl_down(s, off2, 32);
    if (l32 == 0) sq[sqi] = s;
  }
}

// ------------------------------------------------------------ pass A (MFMA)
__global__ __launch_bounds__(256, 2)
void passA_kernel(const unsigned short* __restrict__ zbf, const unsigned short* __restrict__ ebf,
                  const float* __restrict__ e_sq, __half* __restrict__ tm) {
  const int n    = blockIdx.z;
  const int w    = threadIdx.x >> 6, lane = threadIdx.x & 63;
  const int quad = lane >> 4, c16 = lane & 15;
  const int cb   = blockIdx.x * 256 + w * 64;
  const int rg   = blockIdx.y * 512;

  const unsigned short* en = ebf + (size_t)n * 2097152;
  const unsigned short* zn = zbf + (size_t)n * 2097152;
  const float* esq = e_sq + n * KCODES;
  __half* tmn = tm + (size_t)n * (BROWS * NWIN);

  short8 areg[8][4];
  #pragma unroll
  for (int k0 = 0; k0 < 8; ++k0)
    #pragma unroll
    for (int mf = 0; mf < 4; ++mf)
      areg[k0][mf] = *(const short8*)(en + (size_t)((cb >> 4) + mf) * 4096 + k0 * 512 + lane * 8);

  float eq[4][4];
  #pragma unroll
  for (int mf = 0; mf < 4; ++mf) {
    int kb = cb + mf * 16 + quad * 4;
    #pragma unroll
    for (int i = 0; i < 4; ++i) eq[mf][i] = esq[kb + i];
  }

  for (int nt = 0; nt < 8; ++nt) {
    const int rowbase = rg + nt * 64;

    floatx4 acc[4][4];
    #pragma unroll
    for (int i = 0; i < 4; ++i)
      #pragma unroll
      for (int j = 0; j < 4; ++j) acc[i][j] = (floatx4){0.f, 0.f, 0.f, 0.f};

    #pragma unroll
    for (int k0 = 0; k0 < 8; ++k0) {
      short8 b[4];
      #pragma unroll
      for (int nf = 0; nf < 4; ++nf)
        b[nf] = *(const short8*)(zn + (size_t)((rowbase >> 4) + nf) * 4096 + k0 * 512 + lane * 8);
      #pragma unroll
      for (int mf = 0; mf < 4; ++mf)
        #pragma unroll
        for (int nf = 0; nf < 4; ++nf)
          acc[mf][nf] = __builtin_amdgcn_mfma_f32_16x16x32_bf16(areg[k0][mf], b[nf], acc[mf][nf], 0, 0, 0);
    }

    #pragma unroll
    for (int nf = 0; nf < 4; ++nf) {
      float vm[4];
      #pragma unroll
      for (int mf = 0; mf < 4; ++mf) {
        float v = eq[mf][0] - 2.0f * acc[mf][nf][0];
        v = fminf(v, eq[mf][1] - 2.0f * acc[mf][nf][1]);
        v = fminf(v, eq[mf][2] - 2.0f * acc[mf][nf][2]);
        v = fminf(v, eq[mf][3] - 2.0f * acc[mf][nf][3]);
        v = fminf(v, __shfl_xor(v, 16, 64));
        v = fminf(v, __shfl_xor(v, 32, 64));
        vm[mf] = v;
      }
      if (quad == 0) {
        int zr = rowbase + nf * 16 + c16;
        ushort4 o;
        o.x = __half_as_ushort(__float2half(vm[0]));
        o.y = __half_as_ushort(__float2half(vm[1]));
        o.z = __half_as_ushort(__float2half(vm[2]));
        o.w = __half_as_ushort(__float2half(vm[3]));
        *(ushort4*)&tmn[(size_t)zr * NWIN + (cb >> 4)] = o;
      }
    }
  }
}

// ------------------------------------------------------------ passB1 (select)
__global__ __launch_bounds__(256)
void passB1_kernel(const __half* __restrict__ tm, unsigned* __restrict__ queue,
                   unsigned* __restrict__ qtail) {
  __shared__ unsigned buf[4][512];
  __shared__ unsigned wcnt[4];
  __shared__ unsigned pre[4];
  __shared__ unsigned base_sh;

  const int w = threadIdx.x >> 6, lane = threadIdx.x & 63;
  const int gw = blockIdx.x * 4 + w;
  const int r0 = gw * 8;

  uint4 tq[8];
  #pragma unroll
  for (int i = 0; i < 8; ++i) {
    int row = r0 + i;
    int n = row & 1, b = row >> 1;
    tq[i] = *(const uint4*)(tm + ((size_t)n * BROWS + b) * NWIN + lane * 8);
  }

  unsigned cnt = 0;
  #pragma unroll
  for (int i = 0; i < 8; ++i) {
    int row = r0 + i;
    float t[8];
    __half2 h;
    h = *(__half2*)&tq[i].x; t[0] = __low2float(h); t[1] = __high2float(h);
    h = *(__half2*)&tq[i].y; t[2] = __low2float(h); t[3] = __high2float(h);
    h = *(__half2*)&tq[i].z; t[4] = __low2float(h); t[5] = __high2float(h);
    h = *(__half2*)&tq[i].w; t[6] = __low2float(h); t[7] = __high2float(h);
    float mv = t[0];
    #pragma unroll
    for (int j = 1; j < 8; ++j) mv = fminf(mv, t[j]);
    #pragma unroll
    for (int off = 32; off; off >>= 1) mv = fminf(mv, __shfl_xor(mv, off, 64));
    const float thr = mv + EPS;
    #pragma unroll
    for (int j = 0; j < 8; ++j) {
      unsigned long long mb = __ballot(t[j] <= thr);
      while (mb) {
        int src = __ffsll(mb) - 1;
        mb &= mb - 1;
        if (cnt < 512) {
          if (lane == 0) buf[w][cnt] = ((unsigned)row << 16) | (unsigned)(src * 8 + j);
          ++cnt;
        }
      }
    }
  }
  if (lane == 0) wcnt[w] = cnt;
  __syncthreads();
  if (threadIdx.x == 0) {
    unsigned s = 0;
    #pragma unroll
    for (int i = 0; i < 4; ++i) { pre[i] = s; s += wcnt[i]; }
    base_sh = atomicAdd(qtail, s);
  }
  __syncthreads();
  unsigned base = base_sh + pre[w];
  for (unsigned i = lane; i < wcnt[w]; i += 64)
    if (base + i < QCAP) queue[base + i] = buf[w][i];
}

// ------------------------------------------------------------ passB2 (rescore)
// 1024 blocks x 4 waves; each wave processes TWO adjacent queue pairs per
// iteration (both gathers in flight, reduces interleaved). Exact fp32 rescore,
// atomicMin64 winner.
__global__ __launch_bounds__(256)
void passB2_kernel(const float* __restrict__ z, const float* __restrict__ emb,
                   const float* __restrict__ e_sq, const float* __restrict__ z_sq,
                   const unsigned* __restrict__ queue, const unsigned* __restrict__ qtail,
                   unsigned long long* __restrict__ winner) {
  const int w = threadIdx.x >> 6, lane = threadIdx.x & 63;
  const int q = lane & 3, g = lane >> 2;
  unsigned qlen = *qtail;
  if (qlen > QCAP) qlen = QCAP;
  const unsigned wid = blockIdx.x * 4 + w;       // 0..4095
  const unsigned nw = gridDim.x * 4;             // 4096

  for (unsigned base = wid * 2; base < qlen; base += nw * 2) {
    unsigned e0 = queue[base];
    const bool has2 = (base + 1) < qlen;
    unsigned e1 = has2 ? queue[base + 1] : e0;

    int row0 = e0 >> 16, win0 = e0 & 0xFFFF;
    int row1 = e1 >> 16, win1 = e1 & 0xFFFF;
    int code0 = win0 * 16 + g;
    int code1 = win1 * 16 + g;
    const float4* ep0 = (const float4*)(emb + ((size_t)(row0 & 1) * KCODES + code0) * DSUB + q * 64);
    const float4* ep1 = (const float4*)(emb + ((size_t)(row1 & 1) * KCODES + code1) * DSUB + q * 64);
    const float4* zp0 = (const float4*)(z + (size_t)row0 * DSUB + q * 64);
    const float4* zp1 = (const float4*)(z + (size_t)row1 * DSUB + q * 64);

    float s0 = 0.f, s1 = 0.f;
    #pragma unroll
    for (int u = 0; u < 16; ++u) {
      float4 a0 = ep0[u], b0 = zp0[u];
      float4 a1 = ep1[u], b1 = zp1[u];
      s0 += a0.x * b0.x; s0 += a0.y * b0.y; s0 += a0.z * b0.z; s0 += a0.w * b0.w;
      s1 += a1.x * b1.x; s1 += a1.y * b1.y; s1 += a1.z * b1.z; s1 += a1.w * b1.w;
    }
    s0 += __shfl_xor(s0, 1, 64); s1 += __shfl_xor(s1, 1, 64);
    s0 += __shfl_xor(s0, 2, 64); s1 += __shfl_xor(s1, 2, 64);

    float bd0 = (z_sq[row0] - 2.0f * s0) + e_sq[(row0 & 1) * KCODES + code0];
    float bd1 = (z_sq[row1] - 2.0f * s1) + e_sq[(row1 & 1) * KCODES + code1];
    int bk0 = code0, bk1 = code1;
    #pragma unroll
    for (int off = 4; off < 64; off <<= 1) {
      float d0 = __shfl_xor(bd0, off, 64);
      int   k0 = __shfl_xor(bk0, off, 64);
      float d1 = __shfl_xor(bd1, off, 64);
      int   k1 = __shfl_xor(bk1, off, 64);
      if (d0 < bd0 || (d0 == bd0 && k0 < bk0)) { bd0 = d0; bk0 = k0; }
      if (d1 < bd1 || (d1 == bd1 && k1 < bk1)) { bd1 = d1; bk1 = k1; }
    }
    if (lane == 0) {
      atomicMin(&winner[row0], ((unsigned long long)__float_as_uint(bd0) << 32) | (unsigned)bk0);
      if (has2)
        atomicMin(&winner[row1], ((unsigned long long)__float_as_uint(bd1) << 32) | (unsigned)bk1);
    }
  }
}

// ------------------------------------------------------------ passB3 (gather)
__global__ __launch_bounds__(256)
void passB3_kernel(const float* __restrict__ z, const float* __restrict__ emb,
                   const unsigned long long* __restrict__ winner, float* __restrict__ out,
                   int* __restrict__ counts, float* __restrict__ lossarr) {
  const int w = threadIdx.x >> 6, lane = threadIdx.x & 63;
  const int gw = blockIdx.x * 4 + w;        // 0..2047
  float lossacc = 0.f;

  for (int i = 0; i < 4; ++i) {
    int row0 = gw * 8 + i * 2;
    int bk0 = (int)(unsigned)winner[row0];
    int bk1 = (int)(unsigned)winner[row0 + 1];
    const float* eb0 = emb + ((size_t)(row0 & 1) * KCODES + bk0) * DSUB;
    const float* eb1 = emb + ((size_t)((row0 + 1) & 1) * KCODES + bk1) * DSUB;
    float4 ev0 = ((const float4*)eb0)[lane];
    float4 ev1 = ((const float4*)eb1)[lane];
    float4 zv0 = ((const float4*)(z + (size_t)row0 * DSUB))[lane];
    float4 zv1 = ((const float4*)(z + (size_t)(row0 + 1) * DSUB))[lane];
    ((float4*)(out + (size_t)row0 * DSUB))[lane] = ev0;
    ((float4*)(out + (size_t)(row0 + 1) * DSUB))[lane] = ev1;
    float dx = zv0.x - ev0.x, dy = zv0.y - ev0.y, dz = zv0.z - ev0.z, dw = zv0.w - ev0.w;
    lossacc += dx * dx + dy * dy + dz * dz + dw * dw;
    dx = zv1.x - ev1.x; dy = zv1.y - ev1.y; dz = zv1.z - ev1.z; dw = zv1.w - ev1.w;
    lossacc += dx * dx + dy * dy + dz * dz + dw * dw;
    if (lane == 0) {
      out[IDX_OFF + row0] = (float)bk0;
      out[IDX_OFF + row0 + 1] = (float)bk1;
      atomicAdd(&counts[(row0 & 1) * KCODES + bk0], 1);
      atomicAdd(&counts[((row0 + 1) & 1) * KCODES + bk1], 1);
    }
  }
  #pragma unroll
  for (int off = 32; off; off >>= 1) lossacc += __shfl_xor(lossacc, off, 64);
  if (lane == 0) lossarr[gw] = lossacc;
}

// ------------------------------------------------------------ final kernel
__global__ void final_kernel(const int* __restrict__ counts, const float* __restrict__ lossarr,
                             float* __restrict__ out) {
  __shared__ float redh[256];
  __shared__ float redl[256];
  float h = 0.0f, ls = 0.0f;
  for (int k = threadIdx.x; k < KCODES; k += 256) {
    float p = (float)(counts[k] + counts[KCODES + k]) * (1.0f / 16384.0f);
    h -= p * logf(p + 1e-10f);
  }
  for (int k = threadIdx.x; k < 2048; k += 256) ls += lossarr[k];
  redh[threadIdx.x] = h;
  redl[threadIdx.x] = ls;
  __syncthreads();
  for (int s = 128; s; s >>= 1) {
    if (threadIdx.x < s) {
      redh[threadIdx.x] += redh[threadIdx.x + s];
      redl[threadIdx.x] += redl[threadIdx.x + s];
    }
    __syncthreads();
  }
  if (threadIdx.x == 0) {
    out[LOSS_OFF + 0] = 0.25f * redl[0] * (1.0f / (float)QUANT_N);
    out[LOSS_OFF + 1] = 0.0f;
    out[LOSS_OFF + 2] = expf(redh[0]);
  }
}

extern "C" void kernel_launch(void* const* d_in, const int* in_sizes, int n_in,
                              void* d_out, int out_size, void* d_ws, size_t ws_size,
                              hipStream_t stream) {
  const float* z   = (const float*)d_in[0];
  const float* emb = (const float*)d_in[1];
  float* out = (float*)d_out;
  char*  ws  = (char*)d_ws;

  float* e_sq   = (float*)(ws + WS_ESQ);
  float* z_sq   = (float*)(ws + WS_ZSQ);
  int*   counts = (int*)(ws + WS_COUNTS);
  unsigned long long* winner = (unsigned long long*)(ws + WS_WINNER);
  float* lossarr = (float*)(ws + WS_LOSSARR);
  unsigned* qtail = (unsigned*)(ws + WS_QTAIL);
  unsigned short* zbf = (unsigned short*)(ws + WS_ZBF);
  unsigned short* ebf = (unsigned short*)(ws + WS_EBF);
  unsigned* queue = (unsigned*)(ws + WS_QUEUE);
  __half* tmbuf = (__half*)(ws + WS_TM);

  prep_kernel<<<1024, 256, 0, stream>>>(z, emb, e_sq, z_sq, zbf, ebf, counts, winner, qtail);
  dim3 gA(32, 16, 2);
  passA_kernel<<<gA, 256, 0, stream>>>(zbf, ebf, e_sq, tmbuf);
  passB1_kernel<<<512, 256, 0, stream>>>(tmbuf, queue, qtail);
  passB2_kernel<<<1024, 256, 0, stream>>>(z, emb, e_sq, z_sq, queue, qtail, winner);
  passB3_kernel<<<512, 256, 0, stream>>>(z, emb, winner, out, counts, lossarr);
  final_kernel<<<1, 256, 0, stream>>>(counts, lossarr, out);
}

// Round 10
// 305.118 us; speedup vs baseline: 1.0730x; 1.0730x over previous
//
#include <hip/hip_runtime.h>
#include <hip/hip_fp16.h>

// VQ codebook quantization, MI355X.
//   prep:   fp32->bf16 fragment repack + norms + all zero-inits (no memsets).
//   passA:  barrier-free LDS-free bf16 MFMA -> per-(row,16-code-window) minima.
//   passB1: stream tm, per-row min+EPS ballot -> (row,win) pair queue.
//   passB2: wave per pair, ALL 32 gather loads forced into registers before
//           the dot (max MLP), exact fp32 rescore, 64-bit atomicMin winner.
//   passB3: wave per 8 rows: gather quantized, indices, counts, loss partials.
//   final:  perplexity + losses.
// B=8192, d_latent=512, ncb=2, K=8192, d_sub=256.

#define KCODES 8192
#define DSUB   256
#define BROWS  8192
#define NROWS  16384
#define NWIN   512

#define QUANT_N  (BROWS * 512)
#define IDX_OFF  QUANT_N
#define LOSS_OFF (QUANT_N + NROWS)

// ws layout (bytes)
#define WS_ESQ     0          // 16384 f32
#define WS_ZSQ     65536      // 16384 f32
#define WS_COUNTS  131072     // 16384 i32   (zeroed in prep)
#define WS_WINNER  196608     // 16384 u64   (0xFF.. in prep)
#define WS_LOSSARR 327680     // 2048 f32    (every slot written by passB3)
#define WS_QTAIL   335872     // 1 u32       (zeroed in prep)
#define WS_ZBF     1048576    // [2][8192][256] bf16 = 8 MB, fragment layout
#define WS_QUEUE   1048576    // u32 pairs — REUSES zbf (dead after passA)
#define QCAP       2000000
#define WS_EBF     9437184    // [2][8192][256] bf16 = 8 MB, fragment layout
#define WS_TM      17825792   // [2][8192][512] fp16 = 16 MB

#define EPS 2.5e-4f

// Fragment layout (elements, per codebook): row r, element k ->
//   (r>>4)*4096 + (k>>5)*512 + ((k>>3)&3)*128 + (r&15)*8 + (k&7)

typedef __attribute__((ext_vector_type(8))) short short8;
typedef __attribute__((ext_vector_type(8))) unsigned short ushort8v;
typedef __attribute__((ext_vector_type(4))) float floatx4;

__device__ inline unsigned short f2bf(float f) {
  unsigned u = __float_as_uint(f);
  return (unsigned short)((u + 0x7FFFu + ((u >> 16) & 1u)) >> 16);
}

// ------------------------------------------------------------ prep kernel
__global__ void prep_kernel(const float* __restrict__ z, const float* __restrict__ e,
                            float* __restrict__ e_sq, float* __restrict__ z_sq,
                            unsigned short* __restrict__ zbf, unsigned short* __restrict__ ebf,
                            int* __restrict__ counts, unsigned long long* __restrict__ winner,
                            unsigned* __restrict__ qtail) {
  int t = blockIdx.x * 256 + threadIdx.x;
  if (t < 16384) { counts[t] = 0; winner[t] = ~0ull; }
  if (t == 16384) *qtail = 0;

  int gw  = blockIdx.x * 4 + (threadIdx.x >> 6);  // 0..4095
  int l   = threadIdx.x & 63;
  int sub = l >> 5;
  int l32 = l & 31;
  for (int i = 0; i < 4; ++i) {
    int row = i * 8192 + gw * 2 + sub;            // 0..32767 (i<2: emb, else z)
    const float* src;
    unsigned short* dst;
    int r;
    float* sq;
    int sqi;
    if (row < NROWS) {
      src = e + (size_t)row * DSUB;
      dst = ebf; r = row; sq = e_sq; sqi = row;
    } else {
      int rz = row - NROWS;
      int n = rz & 1, b = rz >> 1;
      src = z + (size_t)rz * DSUB;
      dst = zbf + (size_t)n * 2097152; r = b; sq = z_sq; sqi = rz;
    }
    float4 v0 = ((const float4*)src)[2 * l32];
    float4 v1 = ((const float4*)src)[2 * l32 + 1];
    ushort8v o;
    o[0] = f2bf(v0.x); o[1] = f2bf(v0.y); o[2] = f2bf(v0.z); o[3] = f2bf(v0.w);
    o[4] = f2bf(v1.x); o[5] = f2bf(v1.y); o[6] = f2bf(v1.z); o[7] = f2bf(v1.w);
    size_t off = (size_t)(r >> 4) * 4096 + (l32 >> 2) * 512 + (l32 & 3) * 128 + (r & 15) * 8;
    *(ushort8v*)(dst + off) = o;
    float s = v0.x * v0.x + v0.y * v0.y + v0.z * v0.z + v0.w * v0.w
            + v1.x * v1.x + v1.y * v1.y + v1.z * v1.z + v1.w * v1.w;
    #pragma unroll
    for (int off2 = 16; off2; off2 >>= 1) s += __shfl_down(s, off2, 32);
    if (l32 == 0) sq[sqi] = s;
  }
}

// ------------------------------------------------------------ pass A (MFMA)
__global__ __launch_bounds__(256, 2)
void passA_kernel(const unsigned short* __restrict__ zbf, const unsigned short* __restrict__ ebf,
                  const float* __restrict__ e_sq, __half* __restrict__ tm) {
  const int n    = blockIdx.z;
  const int w    = threadIdx.x >> 6, lane = threadIdx.x & 63;
  const int quad = lane >> 4, c16 = lane & 15;
  const int cb   = blockIdx.x * 256 + w * 64;
  const int rg   = blockIdx.y * 512;

  const unsigned short* en = ebf + (size_t)n * 2097152;
  const unsigned short* zn = zbf + (size_t)n * 2097152;
  const float* esq = e_sq + n * KCODES;
  __half* tmn = tm + (size_t)n * (BROWS * NWIN);

  short8 areg[8][4];
  #pragma unroll
  for (int k0 = 0; k0 < 8; ++k0)
    #pragma unroll
    for (int mf = 0; mf < 4; ++mf)
      areg[k0][mf] = *(const short8*)(en + (size_t)((cb >> 4) + mf) * 4096 + k0 * 512 + lane * 8);

  float eq[4][4];
  #pragma unroll
  for (int mf = 0; mf < 4; ++mf) {
    int kb = cb + mf * 16 + quad * 4;
    #pragma unroll
    for (int i = 0; i < 4; ++i) eq[mf][i] = esq[kb + i];
  }

  for (int nt = 0; nt < 8; ++nt) {
    const int rowbase = rg + nt * 64;

    floatx4 acc[4][4];
    #pragma unroll
    for (int i = 0; i < 4; ++i)
      #pragma unroll
      for (int j = 0; j < 4; ++j) acc[i][j] = (floatx4){0.f, 0.f, 0.f, 0.f};

    #pragma unroll
    for (int k0 = 0; k0 < 8; ++k0) {
      short8 b[4];
      #pragma unroll
      for (int nf = 0; nf < 4; ++nf)
        b[nf] = *(const short8*)(zn + (size_t)((rowbase >> 4) + nf) * 4096 + k0 * 512 + lane * 8);
      #pragma unroll
      for (int mf = 0; mf < 4; ++mf)
        #pragma unroll
        for (int nf = 0; nf < 4; ++nf)
          acc[mf][nf] = __builtin_amdgcn_mfma_f32_16x16x32_bf16(areg[k0][mf], b[nf], acc[mf][nf], 0, 0, 0);
    }

    #pragma unroll
    for (int nf = 0; nf < 4; ++nf) {
      float vm[4];
      #pragma unroll
      for (int mf = 0; mf < 4; ++mf) {
        float v = eq[mf][0] - 2.0f * acc[mf][nf][0];
        v = fminf(v, eq[mf][1] - 2.0f * acc[mf][nf][1]);
        v = fminf(v, eq[mf][2] - 2.0f * acc[mf][nf][2]);
        v = fminf(v, eq[mf][3] - 2.0f * acc[mf][nf][3]);
        v = fminf(v, __shfl_xor(v, 16, 64));
        v = fminf(v, __shfl_xor(v, 32, 64));
        vm[mf] = v;
      }
      if (quad == 0) {
        int zr = rowbase + nf * 16 + c16;
        ushort4 o;
        o.x = __half_as_ushort(__float2half(vm[0]));
        o.y = __half_as_ushort(__float2half(vm[1]));
        o.z = __half_as_ushort(__float2half(vm[2]));
        o.w = __half_as_ushort(__float2half(vm[3]));
        *(ushort4*)&tmn[(size_t)zr * NWIN + (cb >> 4)] = o;
      }
    }
  }
}

// ------------------------------------------------------------ passB1 (select)
__global__ __launch_bounds__(256)
void passB1_kernel(const __half* __restrict__ tm, unsigned* __restrict__ queue,
                   unsigned* __restrict__ qtail) {
  __shared__ unsigned buf[4][512];
  __shared__ unsigned wcnt[4];
  __shared__ unsigned pre[4];
  __shared__ unsigned base_sh;

  const int w = threadIdx.x >> 6, lane = threadIdx.x & 63;
  const int gw = blockIdx.x * 4 + w;
  const int r0 = gw * 8;

  uint4 tq[8];
  #pragma unroll
  for (int i = 0; i < 8; ++i) {
    int row = r0 + i;
    int n = row & 1, b = row >> 1;
    tq[i] = *(const uint4*)(tm + ((size_t)n * BROWS + b) * NWIN + lane * 8);
  }

  unsigned cnt = 0;
  #pragma unroll
  for (int i = 0; i < 8; ++i) {
    int row = r0 + i;
    float t[8];
    __half2 h;
    h = *(__half2*)&tq[i].x; t[0] = __low2float(h); t[1] = __high2float(h);
    h = *(__half2*)&tq[i].y; t[2] = __low2float(h); t[3] = __high2float(h);
    h = *(__half2*)&tq[i].z; t[4] = __low2float(h); t[5] = __high2float(h);
    h = *(__half2*)&tq[i].w; t[6] = __low2float(h); t[7] = __high2float(h);
    float mv = t[0];
    #pragma unroll
    for (int j = 1; j < 8; ++j) mv = fminf(mv, t[j]);
    #pragma unroll
    for (int off = 32; off; off >>= 1) mv = fminf(mv, __shfl_xor(mv, off, 64));
    const float thr = mv + EPS;
    #pragma unroll
    for (int j = 0; j < 8; ++j) {
      unsigned long long mb = __ballot(t[j] <= thr);
      while (mb) {
        int src = __ffsll(mb) - 1;
        mb &= mb - 1;
        if (cnt < 512) {
          if (lane == 0) buf[w][cnt] = ((unsigned)row << 16) | (unsigned)(src * 8 + j);
          ++cnt;
        }
      }
    }
  }
  if (lane == 0) wcnt[w] = cnt;
  __syncthreads();
  if (threadIdx.x == 0) {
    unsigned s = 0;
    #pragma unroll
    for (int i = 0; i < 4; ++i) { pre[i] = s; s += wcnt[i]; }
    base_sh = atomicAdd(qtail, s);
  }
  __syncthreads();
  unsigned base = base_sh + pre[w];
  for (unsigned i = lane; i < wcnt[w]; i += 64)
    if (base + i < QCAP) queue[base + i] = buf[w][i];
}

// ------------------------------------------------------------ passB2 (rescore)
// 512 blocks x 4 waves, stride-nw entry assignment (r8's L2-friendly order).
// ALL 32 float4 gathers forced into registers before the dot -> one waitcnt
// per entry, ~32 loads in flight per wave.
__global__ __launch_bounds__(256)
void passB2_kernel(const float* __restrict__ z, const float* __restrict__ emb,
                   const float* __restrict__ e_sq, const float* __restrict__ z_sq,
                   const unsigned* __restrict__ queue, const unsigned* __restrict__ qtail,
                   unsigned long long* __restrict__ winner) {
  const int w = threadIdx.x >> 6, lane = threadIdx.x & 63;
  const int q = lane & 3, g = lane >> 2;
  unsigned qlen = *qtail;
  if (qlen > QCAP) qlen = QCAP;
  const unsigned wid = blockIdx.x * 4 + w;
  const unsigned nw = gridDim.x * 4;

  for (unsigned idx = wid; idx < qlen; idx += nw) {
    unsigned e = queue[idx];
    int row = e >> 16, win = e & 0xFFFF;
    int n = row & 1;
    int code = win * 16 + g;
    const float4* ep = (const float4*)(emb + ((size_t)n * KCODES + code) * DSUB + q * 64);
    const float4* zp = (const float4*)(z + (size_t)row * DSUB + q * 64);

    float4 ev[16], zv[16];
    #pragma unroll
    for (int u = 0; u < 16; ++u) ev[u] = ep[u];
    #pragma unroll
    for (int u = 0; u < 16; ++u) zv[u] = zp[u];

    float s = 0.f;
    #pragma unroll
    for (int u = 0; u < 16; ++u) {
      s += ev[u].x * zv[u].x; s += ev[u].y * zv[u].y;
      s += ev[u].z * zv[u].z; s += ev[u].w * zv[u].w;
    }
    s += __shfl_xor(s, 1, 64);
    s += __shfl_xor(s, 2, 64);

    float bd = (z_sq[row] - 2.0f * s) + e_sq[n * KCODES + code];
    int   bk = code;
    #pragma unroll
    for (int off = 4; off < 64; off <<= 1) {
      float d2 = __shfl_xor(bd, off, 64);
      int   k2 = __shfl_xor(bk, off, 64);
      if (d2 < bd || (d2 == bd && k2 < bk)) { bd = d2; bk = k2; }
    }
    if (lane == 0)
      atomicMin(&winner[row], ((unsigned long long)__float_as_uint(bd) << 32) | (unsigned)bk);
  }
}

// ------------------------------------------------------------ passB3 (gather)
__global__ __launch_bounds__(256)
void passB3_kernel(const float* __restrict__ z, const float* __restrict__ emb,
                   const unsigned long long* __restrict__ winner, float* __restrict__ out,
                   int* __restrict__ counts, float* __restrict__ lossarr) {
  const int w = threadIdx.x >> 6, lane = threadIdx.x & 63;
  const int gw = blockIdx.x * 4 + w;        // 0..2047
  float lossacc = 0.f;

  for (int i = 0; i < 4; ++i) {
    int row0 = gw * 8 + i * 2;
    int bk0 = (int)(unsigned)winner[row0];
    int bk1 = (int)(unsigned)winner[row0 + 1];
    const float* eb0 = emb + ((size_t)(row0 & 1) * KCODES + bk0) * DSUB;
    const float* eb1 = emb + ((size_t)((row0 + 1) & 1) * KCODES + bk1) * DSUB;
    float4 ev0 = ((const float4*)eb0)[lane];
    float4 ev1 = ((const float4*)eb1)[lane];
    float4 zv0 = ((const float4*)(z + (size_t)row0 * DSUB))[lane];
    float4 zv1 = ((const float4*)(z + (size_t)(row0 + 1) * DSUB))[lane];
    ((float4*)(out + (size_t)row0 * DSUB))[lane] = ev0;
    ((float4*)(out + (size_t)(row0 + 1) * DSUB))[lane] = ev1;
    float dx = zv0.x - ev0.x, dy = zv0.y - ev0.y, dz = zv0.z - ev0.z, dw = zv0.w - ev0.w;
    lossacc += dx * dx + dy * dy + dz * dz + dw * dw;
    dx = zv1.x - ev1.x; dy = zv1.y - ev1.y; dz = zv1.z - ev1.z; dw = zv1.w - ev1.w;
    lossacc += dx * dx + dy * dy + dz * dz + dw * dw;
    if (lane == 0) {
      out[IDX_OFF + row0] = (float)bk0;
      out[IDX_OFF + row0 + 1] = (float)bk1;
      atomicAdd(&counts[(row0 & 1) * KCODES + bk0], 1);
      atomicAdd(&counts[((row0 + 1) & 1) * KCODES + bk1], 1);
    }
  }
  #pragma unroll
  for (int off = 32; off; off >>= 1) lossacc += __shfl_xor(lossacc, off, 64);
  if (lane == 0) lossarr[gw] = lossacc;
}

// ------------------------------------------------------------ final kernel
__global__ void final_kernel(const int* __restrict__ counts, const float* __restrict__ lossarr,
                             float* __restrict__ out) {
  __shared__ float redh[256];
  __shared__ float redl[256];
  float h = 0.0f, ls = 0.0f;
  for (int k = threadIdx.x; k < KCODES; k += 256) {
    float p = (float)(counts[k] + counts[KCODES + k]) * (1.0f / 16384.0f);
    h -= p * logf(p + 1e-10f);
  }
  for (int k = threadIdx.x; k < 2048; k += 256) ls += lossarr[k];
  redh[threadIdx.x] = h;
  redl[threadIdx.x] = ls;
  __syncthreads();
  for (int s = 128; s; s >>= 1) {
    if (threadIdx.x < s) {
      redh[threadIdx.x] += redh[threadIdx.x + s];
      redl[threadIdx.x] += redl[threadIdx.x + s];
    }
    __syncthreads();
  }
  if (threadIdx.x == 0) {
    out[LOSS_OFF + 0] = 0.25f * redl[0] * (1.0f / (float)QUANT_N);
    out[LOSS_OFF + 1] = 0.0f;
    out[LOSS_OFF + 2] = expf(redh[0]);
  }
}

extern "C" void kernel_launch(void* const* d_in, const int* in_sizes, int n_in,
                              void* d_out, int out_size, void* d_ws, size_t ws_size,
                              hipStream_t stream) {
  const float* z   = (const float*)d_in[0];
  const float* emb = (const float*)d_in[1];
  float* out = (float*)d_out;
  char*  ws  = (char*)d_ws;

  float* e_sq   = (float*)(ws + WS_ESQ);
  float* z_sq   = (float*)(ws + WS_ZSQ);
  int*   counts = (int*)(ws + WS_COUNTS);
  unsigned long long* winner = (unsigned long long*)(ws + WS_WINNER);
  float* lossarr = (float*)(ws + WS_LOSSARR);
  unsigned* qtail = (unsigned*)(ws + WS_QTAIL);
  unsigned short* zbf = (unsigned short*)(ws + WS_ZBF);
  unsigned short* ebf = (unsigned short*)(ws + WS_EBF);
  unsigned* queue = (unsigned*)(ws + WS_QUEUE);
  __half* tmbuf = (__half*)(ws + WS_TM);

  prep_kernel<<<1024, 256, 0, stream>>>(z, emb, e_sq, z_sq, zbf, ebf, counts, winner, qtail);
  dim3 gA(32, 16, 2);
  passA_kernel<<<gA, 256, 0, stream>>>(zbf, ebf, e_sq, tmbuf);
  passB1_kernel<<<512, 256, 0, stream>>>(tmbuf, queue, qtail);
  passB2_kernel<<<512, 256, 0, stream>>>(z, emb, e_sq, z_sq, queue, qtail, winner);
  passB3_kernel<<<512, 256, 0, stream>>>(z, emb, winner, out, counts, lossarr);
  final_kernel<<<1, 256, 0, stream>>>(counts, lossarr, out);
}

// Round 11
// 253.975 us; speedup vs baseline: 1.2891x; 1.2014x over previous
//
#include <hip/hip_runtime.h>
#include <hip/hip_fp16.h>

// VQ codebook quantization, MI355X.
//   prep:   fp32->bf16 fragment repack + norms + all zero-inits (no memsets).
//   passA:  barrier-free LDS-free bf16 MFMA -> per-(row,16-code-window) minima.
//   passB1: stream tm, per-row min+EPS ballot -> (row,win) pair queue.
//   passB2: wave per pair; LINE-COALESCED gather (4 q-lanes cover one 64B line
//           per code row per instruction), exact fp32 rescore, atomicMin64.
//   passB3: wave per 8 rows: gather quantized, indices, counts, loss partials.
//   final:  perplexity + losses.
// B=8192, d_latent=512, ncb=2, K=8192, d_sub=256.

#define KCODES 8192
#define DSUB   256
#define BROWS  8192
#define NROWS  16384
#define NWIN   512

#define QUANT_N  (BROWS * 512)
#define IDX_OFF  QUANT_N
#define LOSS_OFF (QUANT_N + NROWS)

// ws layout (bytes)
#define WS_ESQ     0          // 16384 f32
#define WS_ZSQ     65536      // 16384 f32
#define WS_COUNTS  131072     // 16384 i32   (zeroed in prep)
#define WS_WINNER  196608     // 16384 u64   (0xFF.. in prep)
#define WS_LOSSARR 327680     // 2048 f32    (every slot written by passB3)
#define WS_QTAIL   335872     // 1 u32       (zeroed in prep)
#define WS_ZBF     1048576    // [2][8192][256] bf16 = 8 MB, fragment layout
#define WS_QUEUE   1048576    // u32 pairs — REUSES zbf (dead after passA)
#define QCAP       2000000
#define WS_EBF     9437184    // [2][8192][256] bf16 = 8 MB, fragment layout
#define WS_TM      17825792   // [2][8192][512] fp16 = 16 MB

#define EPS 2.5e-4f

// Fragment layout (elements, per codebook): row r, element k ->
//   (r>>4)*4096 + (k>>5)*512 + ((k>>3)&3)*128 + (r&15)*8 + (k&7)

typedef __attribute__((ext_vector_type(8))) short short8;
typedef __attribute__((ext_vector_type(8))) unsigned short ushort8v;
typedef __attribute__((ext_vector_type(4))) float floatx4;

__device__ inline unsigned short f2bf(float f) {
  unsigned u = __float_as_uint(f);
  return (unsigned short)((u + 0x7FFFu + ((u >> 16) & 1u)) >> 16);
}

// ------------------------------------------------------------ prep kernel
__global__ void prep_kernel(const float* __restrict__ z, const float* __restrict__ e,
                            float* __restrict__ e_sq, float* __restrict__ z_sq,
                            unsigned short* __restrict__ zbf, unsigned short* __restrict__ ebf,
                            int* __restrict__ counts, unsigned long long* __restrict__ winner,
                            unsigned* __restrict__ qtail) {
  int t = blockIdx.x * 256 + threadIdx.x;
  if (t < 16384) { counts[t] = 0; winner[t] = ~0ull; }
  if (t == 16384) *qtail = 0;

  int gw  = blockIdx.x * 4 + (threadIdx.x >> 6);  // 0..4095
  int l   = threadIdx.x & 63;
  int sub = l >> 5;
  int l32 = l & 31;
  for (int i = 0; i < 4; ++i) {
    int row = i * 8192 + gw * 2 + sub;            // 0..32767 (i<2: emb, else z)
    const float* src;
    unsigned short* dst;
    int r;
    float* sq;
    int sqi;
    if (row < NROWS) {
      src = e + (size_t)row * DSUB;
      dst = ebf; r = row; sq = e_sq; sqi = row;
    } else {
      int rz = row - NROWS;
      int n = rz & 1, b = rz >> 1;
      src = z + (size_t)rz * DSUB;
      dst = zbf + (size_t)n * 2097152; r = b; sq = z_sq; sqi = rz;
    }
    float4 v0 = ((const float4*)src)[2 * l32];
    float4 v1 = ((const float4*)src)[2 * l32 + 1];
    ushort8v o;
    o[0] = f2bf(v0.x); o[1] = f2bf(v0.y); o[2] = f2bf(v0.z); o[3] = f2bf(v0.w);
    o[4] = f2bf(v1.x); o[5] = f2bf(v1.y); o[6] = f2bf(v1.z); o[7] = f2bf(v1.w);
    size_t off = (size_t)(r >> 4) * 4096 + (l32 >> 2) * 512 + (l32 & 3) * 128 + (r & 15) * 8;
    *(ushort8v*)(dst + off) = o;
    float s = v0.x * v0.x + v0.y * v0.y + v0.z * v0.z + v0.w * v0.w
            + v1.x * v1.x + v1.y * v1.y + v1.z * v1.z + v1.w * v1.w;
    #pragma unroll
    for (int off2 = 16; off2; off2 >>= 1) s += __shfl_down(s, off2, 32);
    if (l32 == 0) sq[sqi] = s;
  }
}

// ------------------------------------------------------------ pass A (MFMA)
__global__ __launch_bounds__(256, 2)
void passA_kernel(const unsigned short* __restrict__ zbf, const unsigned short* __restrict__ ebf,
                  const float* __restrict__ e_sq, __half* __restrict__ tm) {
  const int n    = blockIdx.z;
  const int w    = threadIdx.x >> 6, lane = threadIdx.x & 63;
  const int quad = lane >> 4, c16 = lane & 15;
  const int cb   = blockIdx.x * 256 + w * 64;
  const int rg   = blockIdx.y * 512;

  const unsigned short* en = ebf + (size_t)n * 2097152;
  const unsigned short* zn = zbf + (size_t)n * 2097152;
  const float* esq = e_sq + n * KCODES;
  __half* tmn = tm + (size_t)n * (BROWS * NWIN);

  short8 areg[8][4];
  #pragma unroll
  for (int k0 = 0; k0 < 8; ++k0)
    #pragma unroll
    for (int mf = 0; mf < 4; ++mf)
      areg[k0][mf] = *(const short8*)(en + (size_t)((cb >> 4) + mf) * 4096 + k0 * 512 + lane * 8);

  float eq[4][4];
  #pragma unroll
  for (int mf = 0; mf < 4; ++mf) {
    int kb = cb + mf * 16 + quad * 4;
    #pragma unroll
    for (int i = 0; i < 4; ++i) eq[mf][i] = esq[kb + i];
  }

  for (int nt = 0; nt < 8; ++nt) {
    const int rowbase = rg + nt * 64;

    floatx4 acc[4][4];
    #pragma unroll
    for (int i = 0; i < 4; ++i)
      #pragma unroll
      for (int j = 0; j < 4; ++j) acc[i][j] = (floatx4){0.f, 0.f, 0.f, 0.f};

    #pragma unroll
    for (int k0 = 0; k0 < 8; ++k0) {
      short8 b[4];
      #pragma unroll
      for (int nf = 0; nf < 4; ++nf)
        b[nf] = *(const short8*)(zn + (size_t)((rowbase >> 4) + nf) * 4096 + k0 * 512 + lane * 8);
      #pragma unroll
      for (int mf = 0; mf < 4; ++mf)
        #pragma unroll
        for (int nf = 0; nf < 4; ++nf)
          acc[mf][nf] = __builtin_amdgcn_mfma_f32_16x16x32_bf16(areg[k0][mf], b[nf], acc[mf][nf], 0, 0, 0);
    }

    #pragma unroll
    for (int nf = 0; nf < 4; ++nf) {
      float vm[4];
      #pragma unroll
      for (int mf = 0; mf < 4; ++mf) {
        float v = eq[mf][0] - 2.0f * acc[mf][nf][0];
        v = fminf(v, eq[mf][1] - 2.0f * acc[mf][nf][1]);
        v = fminf(v, eq[mf][2] - 2.0f * acc[mf][nf][2]);
        v = fminf(v, eq[mf][3] - 2.0f * acc[mf][nf][3]);
        v = fminf(v, __shfl_xor(v, 16, 64));
        v = fminf(v, __shfl_xor(v, 32, 64));
        vm[mf] = v;
      }
      if (quad == 0) {
        int zr = rowbase + nf * 16 + c16;
        ushort4 o;
        o.x = __half_as_ushort(__float2half(vm[0]));
        o.y = __half_as_ushort(__float2half(vm[1]));
        o.z = __half_as_ushort(__float2half(vm[2]));
        o.w = __half_as_ushort(__float2half(vm[3]));
        *(ushort4*)&tmn[(size_t)zr * NWIN + (cb >> 4)] = o;
      }
    }
  }
}

// ------------------------------------------------------------ passB1 (select)
__global__ __launch_bounds__(256)
void passB1_kernel(const __half* __restrict__ tm, unsigned* __restrict__ queue,
                   unsigned* __restrict__ qtail) {
  __shared__ unsigned buf[4][512];
  __shared__ unsigned wcnt[4];
  __shared__ unsigned pre[4];
  __shared__ unsigned base_sh;

  const int w = threadIdx.x >> 6, lane = threadIdx.x & 63;
  const int gw = blockIdx.x * 4 + w;
  const int r0 = gw * 8;

  uint4 tq[8];
  #pragma unroll
  for (int i = 0; i < 8; ++i) {
    int row = r0 + i;
    int n = row & 1, b = row >> 1;
    tq[i] = *(const uint4*)(tm + ((size_t)n * BROWS + b) * NWIN + lane * 8);
  }

  unsigned cnt = 0;
  #pragma unroll
  for (int i = 0; i < 8; ++i) {
    int row = r0 + i;
    float t[8];
    __half2 h;
    h = *(__half2*)&tq[i].x; t[0] = __low2float(h); t[1] = __high2float(h);
    h = *(__half2*)&tq[i].y; t[2] = __low2float(h); t[3] = __high2float(h);
    h = *(__half2*)&tq[i].z; t[4] = __low2float(h); t[5] = __high2float(h);
    h = *(__half2*)&tq[i].w; t[6] = __low2float(h); t[7] = __high2float(h);
    float mv = t[0];
    #pragma unroll
    for (int j = 1; j < 8; ++j) mv = fminf(mv, t[j]);
    #pragma unroll
    for (int off = 32; off; off >>= 1) mv = fminf(mv, __shfl_xor(mv, off, 64));
    const float thr = mv + EPS;
    #pragma unroll
    for (int j = 0; j < 8; ++j) {
      unsigned long long mb = __ballot(t[j] <= thr);
      while (mb) {
        int src = __ffsll(mb) - 1;
        mb &= mb - 1;
        if (cnt < 512) {
          if (lane == 0) buf[w][cnt] = ((unsigned)row << 16) | (unsigned)(src * 8 + j);
          ++cnt;
        }
      }
    }
  }
  if (lane == 0) wcnt[w] = cnt;
  __syncthreads();
  if (threadIdx.x == 0) {
    unsigned s = 0;
    #pragma unroll
    for (int i = 0; i < 4; ++i) { pre[i] = s; s += wcnt[i]; }
    base_sh = atomicAdd(qtail, s);
  }
  __syncthreads();
  unsigned base = base_sh + pre[w];
  for (unsigned i = lane; i < wcnt[w]; i += 64)
    if (base + i < QCAP) queue[base + i] = buf[w][i];
}

// ------------------------------------------------------------ passB2 (rescore)
// 512 blocks x 4 waves, stride-nw entry assignment. Line-coalesced gather:
// lane (g,q) reads float4 index q+4u of code row g -> each instruction's 4
// q-lanes cover ONE 64B line per row (16 fully-used lines/instr, was 64x16B).
__global__ __launch_bounds__(256)
void passB2_kernel(const float* __restrict__ z, const float* __restrict__ emb,
                   const float* __restrict__ e_sq, const float* __restrict__ z_sq,
                   const unsigned* __restrict__ queue, const unsigned* __restrict__ qtail,
                   unsigned long long* __restrict__ winner) {
  const int w = threadIdx.x >> 6, lane = threadIdx.x & 63;
  const int q = lane & 3, g = lane >> 2;
  unsigned qlen = *qtail;
  if (qlen > QCAP) qlen = QCAP;
  const unsigned wid = blockIdx.x * 4 + w;
  const unsigned nw = gridDim.x * 4;

  for (unsigned idx = wid; idx < qlen; idx += nw) {
    unsigned e = queue[idx];
    int row = e >> 16, win = e & 0xFFFF;
    int n = row & 1;
    int code = win * 16 + g;
    const float4* ep = (const float4*)(emb + ((size_t)n * KCODES + code) * DSUB);
    const float4* zp = (const float4*)(z + (size_t)row * DSUB);

    float s = 0.f;
    #pragma unroll
    for (int u = 0; u < 16; ++u) {
      float4 ev = ep[q + 4 * u];
      float4 zv = zp[q + 4 * u];
      s += ev.x * zv.x; s += ev.y * zv.y; s += ev.z * zv.z; s += ev.w * zv.w;
    }
    s += __shfl_xor(s, 1, 64);
    s += __shfl_xor(s, 2, 64);

    float bd = (z_sq[row] - 2.0f * s) + e_sq[n * KCODES + code];
    int   bk = code;
    #pragma unroll
    for (int off = 4; off < 64; off <<= 1) {
      float d2 = __shfl_xor(bd, off, 64);
      int   k2 = __shfl_xor(bk, off, 64);
      if (d2 < bd || (d2 == bd && k2 < bk)) { bd = d2; bk = k2; }
    }
    if (lane == 0)
      atomicMin(&winner[row], ((unsigned long long)__float_as_uint(bd) << 32) | (unsigned)bk);
  }
}

// ------------------------------------------------------------ passB3 (gather)
__global__ __launch_bounds__(256)
void passB3_kernel(const float* __restrict__ z, const float* __restrict__ emb,
                   const unsigned long long* __restrict__ winner, float* __restrict__ out,
                   int* __restrict__ counts, float* __restrict__ lossarr) {
  const int w = threadIdx.x >> 6, lane = threadIdx.x & 63;
  const int gw = blockIdx.x * 4 + w;        // 0..2047
  float lossacc = 0.f;

  for (int i = 0; i < 4; ++i) {
    int row0 = gw * 8 + i * 2;
    int bk0 = (int)(unsigned)winner[row0];
    int bk1 = (int)(unsigned)winner[row0 + 1];
    const float* eb0 = emb + ((size_t)(row0 & 1) * KCODES + bk0) * DSUB;
    const float* eb1 = emb + ((size_t)((row0 + 1) & 1) * KCODES + bk1) * DSUB;
    float4 ev0 = ((const float4*)eb0)[lane];
    float4 ev1 = ((const float4*)eb1)[lane];
    float4 zv0 = ((const float4*)(z + (size_t)row0 * DSUB))[lane];
    float4 zv1 = ((const float4*)(z + (size_t)(row0 + 1) * DSUB))[lane];
    ((float4*)(out + (size_t)row0 * DSUB))[lane] = ev0;
    ((float4*)(out + (size_t)(row0 + 1) * DSUB))[lane] = ev1;
    float dx = zv0.x - ev0.x, dy = zv0.y - ev0.y, dz = zv0.z - ev0.z, dw = zv0.w - ev0.w;
    lossacc += dx * dx + dy * dy + dz * dz + dw * dw;
    dx = zv1.x - ev1.x; dy = zv1.y - ev1.y; dz = zv1.z - ev1.z; dw = zv1.w - ev1.w;
    lossacc += dx * dx + dy * dy + dz * dz + dw * dw;
    if (lane == 0) {
      out[IDX_OFF + row0] = (float)bk0;
      out[IDX_OFF + row0 + 1] = (float)bk1;
      atomicAdd(&counts[(row0 & 1) * KCODES + bk0], 1);
      atomicAdd(&counts[((row0 + 1) & 1) * KCODES + bk1], 1);
    }
  }
  #pragma unroll
  for (int off = 32; off; off >>= 1) lossacc += __shfl_xor(lossacc, off, 64);
  if (lane == 0) lossarr[gw] = lossacc;
}

// ------------------------------------------------------------ final kernel
__global__ void final_kernel(const int* __restrict__ counts, const float* __restrict__ lossarr,
                             float* __restrict__ out) {
  __shared__ float redh[256];
  __shared__ float redl[256];
  float h = 0.0f, ls = 0.0f;
  for (int k = threadIdx.x; k < KCODES; k += 256) {
    float p = (float)(counts[k] + counts[KCODES + k]) * (1.0f / 16384.0f);
    h -= p * logf(p + 1e-10f);
  }
  for (int k = threadIdx.x; k < 2048; k += 256) ls += lossarr[k];
  redh[threadIdx.x] = h;
  redl[threadIdx.x] = ls;
  __syncthreads();
  for (int s = 128; s; s >>= 1) {
    if (threadIdx.x < s) {
      redh[threadIdx.x] += redh[threadIdx.x + s];
      redl[threadIdx.x] += redl[threadIdx.x + s];
    }
    __syncthreads();
  }
  if (threadIdx.x == 0) {
    out[LOSS_OFF + 0] = 0.25f * redl[0] * (1.0f / (float)QUANT_N);
    out[LOSS_OFF + 1] = 0.0f;
    out[LOSS_OFF + 2] = expf(redh[0]);
  }
}

extern "C" void kernel_launch(void* const* d_in, const int* in_sizes, int n_in,
                              void* d_out, int out_size, void* d_ws, size_t ws_size,
                              hipStream_t stream) {
  const float* z   = (const float*)d_in[0];
  const float* emb = (const float*)d_in[1];
  float* out = (float*)d_out;
  char*  ws  = (char*)d_ws;

  float* e_sq   = (float*)(ws + WS_ESQ);
  float* z_sq   = (float*)(ws + WS_ZSQ);
  int*   counts = (int*)(ws + WS_COUNTS);
  unsigned long long* winner = (unsigned long long*)(ws + WS_WINNER);
  float* lossarr = (float*)(ws + WS_LOSSARR);
  unsigned* qtail = (unsigned*)(ws + WS_QTAIL);
  unsigned short* zbf = (unsigned short*)(ws + WS_ZBF);
  unsigned short* ebf = (unsigned short*)(ws + WS_EBF);
  unsigned* queue = (unsigned*)(ws + WS_QUEUE);
  __half* tmbuf = (__half*)(ws + WS_TM);

  prep_kernel<<<1024, 256, 0, stream>>>(z, emb, e_sq, z_sq, zbf, ebf, counts, winner, qtail);
  dim3 gA(32, 16, 2);
  passA_kernel<<<gA, 256, 0, stream>>>(zbf, ebf, e_sq, tmbuf);
  passB1_kernel<<<512, 256, 0, stream>>>(tmbuf, queue, qtail);
  passB2_kernel<<<512, 256, 0, stream>>>(z, emb, e_sq, z_sq, queue, qtail, winner);
  passB3_kernel<<<512, 256, 0, stream>>>(z, emb, winner, out, counts, lossarr);
  final_kernel<<<1, 256, 0, stream>>>(counts, lossarr, out);
}

// Round 12
// 229.241 us; speedup vs baseline: 1.4282x; 1.1079x over previous
//
#include <hip/hip_runtime.h>
#include <hip/hip_fp16.h>

// VQ codebook quantization, MI355X.
//   prep:   fp32->bf16 fragment repack + norms + all zero-inits (no memsets).
//   passA:  bf16 MFMA, A-frags in registers (64 codes/wave), B tile staged in
//           LDS once per block (4x less L2 traffic), double-buffered.
//   passB1: stream tm, per-row min+EPS ballot -> (row,win) pair queue.
//   passB2: wave per pair; line-coalesced gather, exact fp32 rescore, atomicMin64.
//   passB3: wave per 8 rows: gather quantized, indices, counts, loss partials.
//   final:  perplexity + losses.
// B=8192, d_latent=512, ncb=2, K=8192, d_sub=256.

#define KCODES 8192
#define DSUB   256
#define BROWS  8192
#define NROWS  16384
#define NWIN   512

#define QUANT_N  (BROWS * 512)
#define IDX_OFF  QUANT_N
#define LOSS_OFF (QUANT_N + NROWS)

// ws layout (bytes)
#define WS_ESQ     0          // 16384 f32
#define WS_ZSQ     65536      // 16384 f32
#define WS_COUNTS  131072     // 16384 i32   (zeroed in prep)
#define WS_WINNER  196608     // 16384 u64   (0xFF.. in prep)
#define WS_LOSSARR 327680     // 2048 f32    (every slot written by passB3)
#define WS_QTAIL   335872     // 1 u32       (zeroed in prep)
#define WS_ZBF     1048576    // [2][8192][256] bf16 = 8 MB, fragment layout
#define WS_QUEUE   1048576    // u32 pairs — REUSES zbf (dead after passA)
#define QCAP       2000000
#define WS_EBF     9437184    // [2][8192][256] bf16 = 8 MB, fragment layout
#define WS_TM      17825792   // [2][8192][512] fp16 = 16 MB

#define EPS 2.5e-4f

// Fragment layout (elements, per codebook): row r, element k ->
//   (r>>4)*4096 + (k>>5)*512 + ((k>>3)&3)*128 + (r&15)*8 + (k&7)
// -> any 64-row group's 256-dim fragments occupy a CONTIGUOUS 32KB span.

typedef __attribute__((ext_vector_type(8))) short short8;
typedef __attribute__((ext_vector_type(8))) unsigned short ushort8v;
typedef __attribute__((ext_vector_type(4))) float floatx4;

__device__ inline void gl2lds16(const void* g, void* l) {
  __builtin_amdgcn_global_load_lds(
      (const __attribute__((address_space(1))) void*)g,
      (__attribute__((address_space(3))) void*)l, 16, 0, 0);
}

__device__ inline unsigned short f2bf(float f) {
  unsigned u = __float_as_uint(f);
  return (unsigned short)((u + 0x7FFFu + ((u >> 16) & 1u)) >> 16);
}

// ------------------------------------------------------------ prep kernel
__global__ void prep_kernel(const float* __restrict__ z, const float* __restrict__ e,
                            float* __restrict__ e_sq, float* __restrict__ z_sq,
                            unsigned short* __restrict__ zbf, unsigned short* __restrict__ ebf,
                            int* __restrict__ counts, unsigned long long* __restrict__ winner,
                            unsigned* __restrict__ qtail) {
  int t = blockIdx.x * 256 + threadIdx.x;
  if (t < 16384) { counts[t] = 0; winner[t] = ~0ull; }
  if (t == 16384) *qtail = 0;

  int gw  = blockIdx.x * 4 + (threadIdx.x >> 6);  // 0..4095
  int l   = threadIdx.x & 63;
  int sub = l >> 5;
  int l32 = l & 31;
  for (int i = 0; i < 4; ++i) {
    int row = i * 8192 + gw * 2 + sub;            // 0..32767 (i<2: emb, else z)
    const float* src;
    unsigned short* dst;
    int r;
    float* sq;
    int sqi;
    if (row < NROWS) {
      src = e + (size_t)row * DSUB;
      dst = ebf; r = row; sq = e_sq; sqi = row;
    } else {
      int rz = row - NROWS;
      int n = rz & 1, b = rz >> 1;
      src = z + (size_t)rz * DSUB;
      dst = zbf + (size_t)n * 2097152; r = b; sq = z_sq; sqi = rz;
    }
    float4 v0 = ((const float4*)src)[2 * l32];
    float4 v1 = ((const float4*)src)[2 * l32 + 1];
    ushort8v o;
    o[0] = f2bf(v0.x); o[1] = f2bf(v0.y); o[2] = f2bf(v0.z); o[3] = f2bf(v0.w);
    o[4] = f2bf(v1.x); o[5] = f2bf(v1.y); o[6] = f2bf(v1.z); o[7] = f2bf(v1.w);
    size_t off = (size_t)(r >> 4) * 4096 + (l32 >> 2) * 512 + (l32 & 3) * 128 + (r & 15) * 8;
    *(ushort8v*)(dst + off) = o;
    float s = v0.x * v0.x + v0.y * v0.y + v0.z * v0.z + v0.w * v0.w
            + v1.x * v1.x + v1.y * v1.y + v1.z * v1.z + v1.w * v1.w;
    #pragma unroll
    for (int off2 = 16; off2; off2 >>= 1) s += __shfl_down(s, off2, 32);
    if (l32 == 0) sq[sqi] = s;
  }
}

// ------------------------------------------------------------ pass A (MFMA)
// Grid (32, 16, 2), 256 threads. Block = 256 codes x 512 rows (8 nt of 64).
// Wave w holds codes cb..cb+64 in registers; B 64-row tile staged in LDS once
// per block per nt (double-buffered), shared by all 4 waves.
__global__ __launch_bounds__(256, 2)
void passA_kernel(const unsigned short* __restrict__ zbf, const unsigned short* __restrict__ ebf,
                  const float* __restrict__ e_sq, __half* __restrict__ tm) {
  __shared__ unsigned short Bs[2][16384];         // 2 x 32KB

  const int n    = blockIdx.z;
  const int tid  = threadIdx.x;
  const int w    = tid >> 6, lane = tid & 63;
  const int quad = lane >> 4, c16 = lane & 15;
  const int cb   = blockIdx.x * 256 + w * 64;
  const int rg   = blockIdx.y * 512;

  const unsigned short* en = ebf + (size_t)n * 2097152;
  const unsigned short* zn = zbf + (size_t)n * 2097152;
  const float* esq = e_sq + n * KCODES;
  __half* tmn = tm + (size_t)n * (BROWS * NWIN);

  // A fragments: 64 codes x 256 dims, 8 k-steps x 4 mf, 1KB coalesced each.
  short8 areg[8][4];
  #pragma unroll
  for (int k0 = 0; k0 < 8; ++k0)
    #pragma unroll
    for (int mf = 0; mf < 4; ++mf)
      areg[k0][mf] = *(const short8*)(en + (size_t)((cb >> 4) + mf) * 4096 + k0 * 512 + lane * 8);

  float eq[4][4];
  #pragma unroll
  for (int mf = 0; mf < 4; ++mf) {
    int kb = cb + mf * 16 + quad * 4;
    #pragma unroll
    for (int i = 0; i < 4; ++i) eq[mf][i] = esq[kb + i];
  }

  // stage 32KB (64-row fragment span) into LDS buffer: 8 instr x 4KB,
  // wave w covers bytes [i*4KB + w*1KB, +1KB)
  const unsigned short* zg = zn + (size_t)(rg >> 4) * 4096;
  {
    const int eo = w * 512 + lane * 8;
    #pragma unroll
    for (int i = 0; i < 8; ++i)
      gl2lds16(zg + i * 2048 + eo, &Bs[0][i * 2048 + w * 512]);
  }

  for (int nt = 0; nt < 8; ++nt) {
    __syncthreads();            // staged buffer ready; prev buffer readers done
    if (nt < 7) {
      const unsigned short* zs = zg + (nt + 1) * 16384;
      unsigned short* ld = &Bs[(nt + 1) & 1][0];
      const int eo = w * 512 + lane * 8;
      #pragma unroll
      for (int i = 0; i < 8; ++i)
        gl2lds16(zs + i * 2048 + eo, ld + i * 2048 + w * 512);
    }
    const unsigned short* bsrc = &Bs[nt & 1][0];
    const int rowbase = rg + nt * 64;

    floatx4 acc[4][4];
    #pragma unroll
    for (int i = 0; i < 4; ++i)
      #pragma unroll
      for (int j = 0; j < 4; ++j) acc[i][j] = (floatx4){0.f, 0.f, 0.f, 0.f};

    #pragma unroll
    for (int k0 = 0; k0 < 8; ++k0) {
      short8 b[4];
      #pragma unroll
      for (int nf = 0; nf < 4; ++nf)
        b[nf] = *(const short8*)&bsrc[nf * 4096 + k0 * 512 + lane * 8];
      #pragma unroll
      for (int mf = 0; mf < 4; ++mf)
        #pragma unroll
        for (int nf = 0; nf < 4; ++nf)
          acc[mf][nf] = __builtin_amdgcn_mfma_f32_16x16x32_bf16(areg[k0][mf], b[nf], acc[mf][nf], 0, 0, 0);
    }

    // epilogue: per-mf (16-code window) min of e_sq[k] - 2*c, per z-row column
    #pragma unroll
    for (int nf = 0; nf < 4; ++nf) {
      float vm[4];
      #pragma unroll
      for (int mf = 0; mf < 4; ++mf) {
        float v = eq[mf][0] - 2.0f * acc[mf][nf][0];
        v = fminf(v, eq[mf][1] - 2.0f * acc[mf][nf][1]);
        v = fminf(v, eq[mf][2] - 2.0f * acc[mf][nf][2]);
        v = fminf(v, eq[mf][3] - 2.0f * acc[mf][nf][3]);
        v = fminf(v, __shfl_xor(v, 16, 64));
        v = fminf(v, __shfl_xor(v, 32, 64));
        vm[mf] = v;
      }
      if (quad == 0) {
        int zr = rowbase + nf * 16 + c16;
        ushort4 o;
        o.x = __half_as_ushort(__float2half(vm[0]));
        o.y = __half_as_ushort(__float2half(vm[1]));
        o.z = __half_as_ushort(__float2half(vm[2]));
        o.w = __half_as_ushort(__float2half(vm[3]));
        *(ushort4*)&tmn[(size_t)zr * NWIN + (cb >> 4)] = o;
      }
    }
  }
}

// ------------------------------------------------------------ passB1 (select)
__global__ __launch_bounds__(256)
void passB1_kernel(const __half* __restrict__ tm, unsigned* __restrict__ queue,
                   unsigned* __restrict__ qtail) {
  __shared__ unsigned buf[4][512];
  __shared__ unsigned wcnt[4];
  __shared__ unsigned pre[4];
  __shared__ unsigned base_sh;

  const int w = threadIdx.x >> 6, lane = threadIdx.x & 63;
  const int gw = blockIdx.x * 4 + w;
  const int r0 = gw * 8;

  uint4 tq[8];
  #pragma unroll
  for (int i = 0; i < 8; ++i) {
    int row = r0 + i;
    int n = row & 1, b = row >> 1;
    tq[i] = *(const uint4*)(tm + ((size_t)n * BROWS + b) * NWIN + lane * 8);
  }

  unsigned cnt = 0;
  #pragma unroll
  for (int i = 0; i < 8; ++i) {
    int row = r0 + i;
    float t[8];
    __half2 h;
    h = *(__half2*)&tq[i].x; t[0] = __low2float(h); t[1] = __high2float(h);
    h = *(__half2*)&tq[i].y; t[2] = __low2float(h); t[3] = __high2float(h);
    h = *(__half2*)&tq[i].z; t[4] = __low2float(h); t[5] = __high2float(h);
    h = *(__half2*)&tq[i].w; t[6] = __low2float(h); t[7] = __high2float(h);
    float mv = t[0];
    #pragma unroll
    for (int j = 1; j < 8; ++j) mv = fminf(mv, t[j]);
    #pragma unroll
    for (int off = 32; off; off >>= 1) mv = fminf(mv, __shfl_xor(mv, off, 64));
    const float thr = mv + EPS;
    #pragma unroll
    for (int j = 0; j < 8; ++j) {
      unsigned long long mb = __ballot(t[j] <= thr);
      while (mb) {
        int src = __ffsll(mb) - 1;
        mb &= mb - 1;
        if (cnt < 512) {
          if (lane == 0) buf[w][cnt] = ((unsigned)row << 16) | (unsigned)(src * 8 + j);
          ++cnt;
        }
      }
    }
  }
  if (lane == 0) wcnt[w] = cnt;
  __syncthreads();
  if (threadIdx.x == 0) {
    unsigned s = 0;
    #pragma unroll
    for (int i = 0; i < 4; ++i) { pre[i] = s; s += wcnt[i]; }
    base_sh = atomicAdd(qtail, s);
  }
  __syncthreads();
  unsigned base = base_sh + pre[w];
  for (unsigned i = lane; i < wcnt[w]; i += 64)
    if (base + i < QCAP) queue[base + i] = buf[w][i];
}

// ------------------------------------------------------------ passB2 (rescore)
// 512 blocks x 4 waves, stride-nw entry assignment. Line-coalesced gather:
// lane (g,q) reads float4 index q+4u of code row g.
__global__ __launch_bounds__(256)
void passB2_kernel(const float* __restrict__ z, const float* __restrict__ emb,
                   const float* __restrict__ e_sq, const float* __restrict__ z_sq,
                   const unsigned* __restrict__ queue, const unsigned* __restrict__ qtail,
                   unsigned long long* __restrict__ winner) {
  const int w = threadIdx.x >> 6, lane = threadIdx.x & 63;
  const int q = lane & 3, g = lane >> 2;
  unsigned qlen = *qtail;
  if (qlen > QCAP) qlen = QCAP;
  const unsigned wid = blockIdx.x * 4 + w;
  const unsigned nw = gridDim.x * 4;

  for (unsigned idx = wid; idx < qlen; idx += nw) {
    unsigned e = queue[idx];
    int row = e >> 16, win = e & 0xFFFF;
    int n = row & 1;
    int code = win * 16 + g;
    const float4* ep = (const float4*)(emb + ((size_t)n * KCODES + code) * DSUB);
    const float4* zp = (const float4*)(z + (size_t)row * DSUB);

    float s = 0.f;
    #pragma unroll
    for (int u = 0; u < 16; ++u) {
      float4 ev = ep[q + 4 * u];
      float4 zv = zp[q + 4 * u];
      s += ev.x * zv.x; s += ev.y * zv.y; s += ev.z * zv.z; s += ev.w * zv.w;
    }
    s += __shfl_xor(s, 1, 64);
    s += __shfl_xor(s, 2, 64);

    float bd = (z_sq[row] - 2.0f * s) + e_sq[n * KCODES + code];
    int   bk = code;
    #pragma unroll
    for (int off = 4; off < 64; off <<= 1) {
      float d2 = __shfl_xor(bd, off, 64);
      int   k2 = __shfl_xor(bk, off, 64);
      if (d2 < bd || (d2 == bd && k2 < bk)) { bd = d2; bk = k2; }
    }
    if (lane == 0)
      atomicMin(&winner[row], ((unsigned long long)__float_as_uint(bd) << 32) | (unsigned)bk);
  }
}

// ------------------------------------------------------------ passB3 (gather)
__global__ __launch_bounds__(256)
void passB3_kernel(const float* __restrict__ z, const float* __restrict__ emb,
                   const unsigned long long* __restrict__ winner, float* __restrict__ out,
                   int* __restrict__ counts, float* __restrict__ lossarr) {
  const int w = threadIdx.x >> 6, lane = threadIdx.x & 63;
  const int gw = blockIdx.x * 4 + w;        // 0..2047
  float lossacc = 0.f;

  for (int i = 0; i < 4; ++i) {
    int row0 = gw * 8 + i * 2;
    int bk0 = (int)(unsigned)winner[row0];
    int bk1 = (int)(unsigned)winner[row0 + 1];
    const float* eb0 = emb + ((size_t)(row0 & 1) * KCODES + bk0) * DSUB;
    const float* eb1 = emb + ((size_t)((row0 + 1) & 1) * KCODES + bk1) * DSUB;
    float4 ev0 = ((const float4*)eb0)[lane];
    float4 ev1 = ((const float4*)eb1)[lane];
    float4 zv0 = ((const float4*)(z + (size_t)row0 * DSUB))[lane];
    float4 zv1 = ((const float4*)(z + (size_t)(row0 + 1) * DSUB))[lane];
    ((float4*)(out + (size_t)row0 * DSUB))[lane] = ev0;
    ((float4*)(out + (size_t)(row0 + 1) * DSUB))[lane] = ev1;
    float dx = zv0.x - ev0.x, dy = zv0.y - ev0.y, dz = zv0.z - ev0.z, dw = zv0.w - ev0.w;
    lossacc += dx * dx + dy * dy + dz * dz + dw * dw;
    dx = zv1.x - ev1.x; dy = zv1.y - ev1.y; dz = zv1.z - ev1.z; dw = zv1.w - ev1.w;
    lossacc += dx * dx + dy * dy + dz * dz + dw * dw;
    if (lane == 0) {
      out[IDX_OFF + row0] = (float)bk0;
      out[IDX_OFF + row0 + 1] = (float)bk1;
      atomicAdd(&counts[(row0 & 1) * KCODES + bk0], 1);
      atomicAdd(&counts[((row0 + 1) & 1) * KCODES + bk1], 1);
    }
  }
  #pragma unroll
  for (int off = 32; off; off >>= 1) lossacc += __shfl_xor(lossacc, off, 64);
  if (lane == 0) lossarr[gw] = lossacc;
}

// ------------------------------------------------------------ final kernel
__global__ void final_kernel(const int* __restrict__ counts, const float* __restrict__ lossarr,
                             float* __restrict__ out) {
  __shared__ float redh[256];
  __shared__ float redl[256];
  float h = 0.0f, ls = 0.0f;
  for (int k = threadIdx.x; k < KCODES; k += 256) {
    float p = (float)(counts[k] + counts[KCODES + k]) * (1.0f / 16384.0f);
    h -= p * logf(p + 1e-10f);
  }
  for (int k = threadIdx.x; k < 2048; k += 256) ls += lossarr[k];
  redh[threadIdx.x] = h;
  redl[threadIdx.x] = ls;
  __syncthreads();
  for (int s = 128; s; s >>= 1) {
    if (threadIdx.x < s) {
      redh[threadIdx.x] += redh[threadIdx.x + s];
      redl[threadIdx.x] += redl[threadIdx.x + s];
    }
    __syncthreads();
  }
  if (threadIdx.x == 0) {
    out[LOSS_OFF + 0] = 0.25f * redl[0] * (1.0f / (float)QUANT_N);
    out[LOSS_OFF + 1] = 0.0f;
    out[LOSS_OFF + 2] = expf(redh[0]);
  }
}

extern "C" void kernel_launch(void* const* d_in, const int* in_sizes, int n_in,
                              void* d_out, int out_size, void* d_ws, size_t ws_size,
                              hipStream_t stream) {
  const float* z   = (const float*)d_in[0];
  const float* emb = (const float*)d_in[1];
  float* out = (float*)d_out;
  char*  ws  = (char*)d_ws;

  float* e_sq   = (float*)(ws + WS_ESQ);
  float* z_sq   = (float*)(ws + WS_ZSQ);
  int*   counts = (int*)(ws + WS_COUNTS);
  unsigned long long* winner = (unsigned long long*)(ws + WS_WINNER);
  float* lossarr = (float*)(ws + WS_LOSSARR);
  unsigned* qtail = (unsigned*)(ws + WS_QTAIL);
  unsigned short* zbf = (unsigned short*)(ws + WS_ZBF);
  unsigned short* ebf = (unsigned short*)(ws + WS_EBF);
  unsigned* queue = (unsigned*)(ws + WS_QUEUE);
  __half* tmbuf = (__half*)(ws + WS_TM);

  prep_kernel<<<1024, 256, 0, stream>>>(z, emb, e_sq, z_sq, zbf, ebf, counts, winner, qtail);
  dim3 gA(32, 16, 2);
  passA_kernel<<<gA, 256, 0, stream>>>(zbf, ebf, e_sq, tmbuf);
  passB1_kernel<<<512, 256, 0, stream>>>(tmbuf, queue, qtail);
  passB2_kernel<<<512, 256, 0, stream>>>(z, emb, e_sq, z_sq, queue, qtail, winner);
  passB3_kernel<<<512, 256, 0, stream>>>(z, emb, winner, out, counts, lossarr);
  final_kernel<<<1, 256, 0, stream>>>(counts, lossarr, out);
}

// Round 13
// 224.112 us; speedup vs baseline: 1.4609x; 1.0229x over previous
//
#include <hip/hip_runtime.h>
#include <hip/hip_fp16.h>

// VQ codebook quantization, MI355X.
//   prep:   fp32->bf16 fragment repack + norms + all zero-inits (no memsets).
//   passA:  bf16 MFMA 32x32x16 (half the MFMA instr of 16x16x32), A-frags in
//           registers (64 codes/wave), B tile staged in LDS (double-buffered).
//   passB1: stream tm, per-row min+EPS ballot -> (row,win) pair queue.
//   passB2: wave per pair; line-coalesced gather, exact fp32 rescore, atomicMin64.
//   passB3: wave per 8 rows: gather quantized, indices, counts, loss partials.
//   final:  perplexity + losses.
// B=8192, d_latent=512, ncb=2, K=8192, d_sub=256.

#define KCODES 8192
#define DSUB   256
#define BROWS  8192
#define NROWS  16384
#define NWIN   512

#define QUANT_N  (BROWS * 512)
#define IDX_OFF  QUANT_N
#define LOSS_OFF (QUANT_N + NROWS)

// ws layout (bytes)
#define WS_ESQ     0          // 16384 f32
#define WS_ZSQ     65536      // 16384 f32
#define WS_COUNTS  131072     // 16384 i32   (zeroed in prep)
#define WS_WINNER  196608     // 16384 u64   (0xFF.. in prep)
#define WS_LOSSARR 327680     // 2048 f32    (every slot written by passB3)
#define WS_QTAIL   335872     // 1 u32       (zeroed in prep)
#define WS_ZBF     1048576    // [2][8192][256] bf16 = 8 MB, fragment layout
#define WS_QUEUE   1048576    // u32 pairs — REUSES zbf (dead after passA)
#define QCAP       2000000
#define WS_EBF     9437184    // [2][8192][256] bf16 = 8 MB, fragment layout
#define WS_TM      17825792   // [2][8192][512] fp16 = 16 MB

#define EPS 2.5e-4f

// Fragment layout (elements, per codebook): row r, element k ->
//   (r>>4)*4096 + (k>>5)*512 + ((k>>3)&3)*128 + (r&15)*8 + (k&7)
// 16x16x32 view: lane (quad,c16) reads short8 at grp*4096 + k0*512 + lane*8.
// 32x32x16 view: lane (l5,c32) reads short8 at
//   (grp + (c32>>4))*4096 + (k0>>1)*512 + (k0&1)*256 + l5*128 + (lane&15)*8.

typedef __attribute__((ext_vector_type(8))) short short8;
typedef __attribute__((ext_vector_type(8))) unsigned short ushort8v;
typedef __attribute__((ext_vector_type(16))) float floatx16;

__device__ inline void gl2lds16(const void* g, void* l) {
  __builtin_amdgcn_global_load_lds(
      (const __attribute__((address_space(1))) void*)g,
      (__attribute__((address_space(3))) void*)l, 16, 0, 0);
}

__device__ inline unsigned short f2bf(float f) {
  unsigned u = __float_as_uint(f);
  return (unsigned short)((u + 0x7FFFu + ((u >> 16) & 1u)) >> 16);
}

// ------------------------------------------------------------ prep kernel
__global__ void prep_kernel(const float* __restrict__ z, const float* __restrict__ e,
                            float* __restrict__ e_sq, float* __restrict__ z_sq,
                            unsigned short* __restrict__ zbf, unsigned short* __restrict__ ebf,
                            int* __restrict__ counts, unsigned long long* __restrict__ winner,
                            unsigned* __restrict__ qtail) {
  int t = blockIdx.x * 256 + threadIdx.x;
  if (t < 16384) { counts[t] = 0; winner[t] = ~0ull; }
  if (t == 16384) *qtail = 0;

  int gw  = blockIdx.x * 4 + (threadIdx.x >> 6);  // 0..4095
  int l   = threadIdx.x & 63;
  int sub = l >> 5;
  int l32 = l & 31;
  for (int i = 0; i < 4; ++i) {
    int row = i * 8192 + gw * 2 + sub;            // 0..32767 (i<2: emb, else z)
    const float* src;
    unsigned short* dst;
    int r;
    float* sq;
    int sqi;
    if (row < NROWS) {
      src = e + (size_t)row * DSUB;
      dst = ebf; r = row; sq = e_sq; sqi = row;
    } else {
      int rz = row - NROWS;
      int n = rz & 1, b = rz >> 1;
      src = z + (size_t)rz * DSUB;
      dst = zbf + (size_t)n * 2097152; r = b; sq = z_sq; sqi = rz;
    }
    float4 v0 = ((const float4*)src)[2 * l32];
    float4 v1 = ((const float4*)src)[2 * l32 + 1];
    ushort8v o;
    o[0] = f2bf(v0.x); o[1] = f2bf(v0.y); o[2] = f2bf(v0.z); o[3] = f2bf(v0.w);
    o[4] = f2bf(v1.x); o[5] = f2bf(v1.y); o[6] = f2bf(v1.z); o[7] = f2bf(v1.w);
    size_t off = (size_t)(r >> 4) * 4096 + (l32 >> 2) * 512 + (l32 & 3) * 128 + (r & 15) * 8;
    *(ushort8v*)(dst + off) = o;
    float s = v0.x * v0.x + v0.y * v0.y + v0.z * v0.z + v0.w * v0.w
            + v1.x * v1.x + v1.y * v1.y + v1.z * v1.z + v1.w * v1.w;
    #pragma unroll
    for (int off2 = 16; off2; off2 >>= 1) s += __shfl_down(s, off2, 32);
    if (l32 == 0) sq[sqi] = s;
  }
}

// ------------------------------------------------------------ pass A (MFMA)
// Grid (32, 16, 2), 256 threads. Block = 256 codes x 512 rows (8 nt of 64).
// Wave w: 64 codes as 2 M-frags of 32; B 64-row tile in LDS (2x2 frag x 16 k).
__global__ __launch_bounds__(256, 2)
void passA_kernel(const unsigned short* __restrict__ zbf, const unsigned short* __restrict__ ebf,
                  const float* __restrict__ e_sq, __half* __restrict__ tm) {
  __shared__ unsigned short Bs[2][16384];         // 2 x 32KB

  const int n    = blockIdx.z;
  const int tid  = threadIdx.x;
  const int w    = tid >> 6, lane = tid & 63;
  const int l5   = lane >> 5, c32 = lane & 31;
  const int cb   = blockIdx.x * 256 + w * 64;
  const int rg   = blockIdx.y * 512;

  const unsigned short* en = ebf + (size_t)n * 2097152;
  const unsigned short* zn = zbf + (size_t)n * 2097152;
  const float* esq = e_sq + n * KCODES;
  __half* tmn = tm + (size_t)n * (BROWS * NWIN);

  // lane-constant fragment address part (elements)
  const int lo = (c32 >> 4) * 4096 + l5 * 128 + (lane & 15) * 8;

  // A fragments: 2 M-frags x 16 k-steps, short8 each (128 VGPR)
  short8 areg[16][2];
  #pragma unroll
  for (int k0 = 0; k0 < 16; ++k0)
    #pragma unroll
    for (int mi = 0; mi < 2; ++mi)
      areg[k0][mi] = *(const short8*)(en + (size_t)((cb >> 4) + mi * 2) * 4096
                                      + (k0 >> 1) * 512 + (k0 & 1) * 256 + lo);

  // e_sq per acc reg: code = cb + mi*32 + (reg&3) + 8*(reg>>2) + 4*l5
  float eq[2][16];
  #pragma unroll
  for (int mi = 0; mi < 2; ++mi)
    #pragma unroll
    for (int reg = 0; reg < 16; ++reg)
      eq[mi][reg] = esq[cb + mi * 32 + (reg & 3) + 8 * (reg >> 2) + 4 * l5];

  // stage first 32KB B tile
  const unsigned short* zg = zn + (size_t)(rg >> 4) * 4096;
  {
    const int eo = w * 512 + lane * 8;
    #pragma unroll
    for (int i = 0; i < 8; ++i)
      gl2lds16(zg + i * 2048 + eo, &Bs[0][i * 2048 + w * 512]);
  }

  for (int nt = 0; nt < 8; ++nt) {
    __syncthreads();            // staged buffer ready; prev buffer readers done
    if (nt < 7) {
      const unsigned short* zs = zg + (nt + 1) * 16384;
      unsigned short* ld = &Bs[(nt + 1) & 1][0];
      const int eo = w * 512 + lane * 8;
      #pragma unroll
      for (int i = 0; i < 8; ++i)
        gl2lds16(zs + i * 2048 + eo, ld + i * 2048 + w * 512);
    }
    const unsigned short* bsrc = &Bs[nt & 1][0];
    const int rowbase = rg + nt * 64;

    floatx16 acc[2][2];
    #pragma unroll
    for (int mi = 0; mi < 2; ++mi)
      #pragma unroll
      for (int nf = 0; nf < 2; ++nf)
        #pragma unroll
        for (int i = 0; i < 16; ++i) acc[mi][nf][i] = 0.f;

    #pragma unroll
    for (int k0 = 0; k0 < 16; ++k0) {
      const int ko = (k0 >> 1) * 512 + (k0 & 1) * 256 + lo;
      short8 b0 = *(const short8*)&bsrc[ko];
      short8 b1 = *(const short8*)&bsrc[8192 + ko];
      acc[0][0] = __builtin_amdgcn_mfma_f32_32x32x16_bf16(areg[k0][0], b0, acc[0][0], 0, 0, 0);
      acc[0][1] = __builtin_amdgcn_mfma_f32_32x32x16_bf16(areg[k0][0], b1, acc[0][1], 0, 0, 0);
      acc[1][0] = __builtin_amdgcn_mfma_f32_32x32x16_bf16(areg[k0][1], b0, acc[1][0], 0, 0, 0);
      acc[1][1] = __builtin_amdgcn_mfma_f32_32x32x16_bf16(areg[k0][1], b1, acc[1][1], 0, 0, 0);
    }

    // epilogue: per (mi, half) = one 16-code window; regs 0-7 / 8-15 + xor32.
    #pragma unroll
    for (int nf = 0; nf < 2; ++nf) {
      float wm[4];
      #pragma unroll
      for (int mi = 0; mi < 2; ++mi) {
        float pA = eq[mi][0] - 2.0f * acc[mi][nf][0];
        float pB = eq[mi][8] - 2.0f * acc[mi][nf][8];
        #pragma unroll
        for (int r = 1; r < 8; ++r) {
          pA = fminf(pA, eq[mi][r] - 2.0f * acc[mi][nf][r]);
          pB = fminf(pB, eq[mi][r + 8] - 2.0f * acc[mi][nf][r + 8]);
        }
        pA = fminf(pA, __shfl_xor(pA, 32, 64));
        pB = fminf(pB, __shfl_xor(pB, 32, 64));
        wm[mi * 2]     = pA;
        wm[mi * 2 + 1] = pB;
      }
      if (l5 == 0) {
        int zr = rowbase + nf * 32 + c32;
        ushort4 o;
        o.x = __half_as_ushort(__float2half(wm[0]));
        o.y = __half_as_ushort(__float2half(wm[1]));
        o.z = __half_as_ushort(__float2half(wm[2]));
        o.w = __half_as_ushort(__float2half(wm[3]));
        *(ushort4*)&tmn[(size_t)zr * NWIN + (cb >> 4)] = o;
      }
    }
  }
}

// ------------------------------------------------------------ passB1 (select)
__global__ __launch_bounds__(256)
void passB1_kernel(const __half* __restrict__ tm, unsigned* __restrict__ queue,
                   unsigned* __restrict__ qtail) {
  __shared__ unsigned buf[4][512];
  __shared__ unsigned wcnt[4];
  __shared__ unsigned pre[4];
  __shared__ unsigned base_sh;

  const int w = threadIdx.x >> 6, lane = threadIdx.x & 63;
  const int gw = blockIdx.x * 4 + w;
  const int r0 = gw * 8;

  uint4 tq[8];
  #pragma unroll
  for (int i = 0; i < 8; ++i) {
    int row = r0 + i;
    int n = row & 1, b = row >> 1;
    tq[i] = *(const uint4*)(tm + ((size_t)n * BROWS + b) * NWIN + lane * 8);
  }

  unsigned cnt = 0;
  #pragma unroll
  for (int i = 0; i < 8; ++i) {
    int row = r0 + i;
    float t[8];
    __half2 h;
    h = *(__half2*)&tq[i].x; t[0] = __low2float(h); t[1] = __high2float(h);
    h = *(__half2*)&tq[i].y; t[2] = __low2float(h); t[3] = __high2float(h);
    h = *(__half2*)&tq[i].z; t[4] = __low2float(h); t[5] = __high2float(h);
    h = *(__half2*)&tq[i].w; t[6] = __low2float(h); t[7] = __high2float(h);
    float mv = t[0];
    #pragma unroll
    for (int j = 1; j < 8; ++j) mv = fminf(mv, t[j]);
    #pragma unroll
    for (int off = 32; off; off >>= 1) mv = fminf(mv, __shfl_xor(mv, off, 64));
    const float thr = mv + EPS;
    #pragma unroll
    for (int j = 0; j < 8; ++j) {
      unsigned long long mb = __ballot(t[j] <= thr);
      while (mb) {
        int src = __ffsll(mb) - 1;
        mb &= mb - 1;
        if (cnt < 512) {
          if (lane == 0) buf[w][cnt] = ((unsigned)row << 16) | (unsigned)(src * 8 + j);
          ++cnt;
        }
      }
    }
  }
  if (lane == 0) wcnt[w] = cnt;
  __syncthreads();
  if (threadIdx.x == 0) {
    unsigned s = 0;
    #pragma unroll
    for (int i = 0; i < 4; ++i) { pre[i] = s; s += wcnt[i]; }
    base_sh = atomicAdd(qtail, s);
  }
  __syncthreads();
  unsigned base = base_sh + pre[w];
  for (unsigned i = lane; i < wcnt[w]; i += 64)
    if (base + i < QCAP) queue[base + i] = buf[w][i];
}

// ------------------------------------------------------------ passB2 (rescore)
__global__ __launch_bounds__(256)
void passB2_kernel(const float* __restrict__ z, const float* __restrict__ emb,
                   const float* __restrict__ e_sq, const float* __restrict__ z_sq,
                   const unsigned* __restrict__ queue, const unsigned* __restrict__ qtail,
                   unsigned long long* __restrict__ winner) {
  const int w = threadIdx.x >> 6, lane = threadIdx.x & 63;
  const int q = lane & 3, g = lane >> 2;
  unsigned qlen = *qtail;
  if (qlen > QCAP) qlen = QCAP;
  const unsigned wid = blockIdx.x * 4 + w;
  const unsigned nw = gridDim.x * 4;

  for (unsigned idx = wid; idx < qlen; idx += nw) {
    unsigned e = queue[idx];
    int row = e >> 16, win = e & 0xFFFF;
    int n = row & 1;
    int code = win * 16 + g;
    const float4* ep = (const float4*)(emb + ((size_t)n * KCODES + code) * DSUB);
    const float4* zp = (const float4*)(z + (size_t)row * DSUB);

    float s = 0.f;
    #pragma unroll
    for (int u = 0; u < 16; ++u) {
      float4 ev = ep[q + 4 * u];
      float4 zv = zp[q + 4 * u];
      s += ev.x * zv.x; s += ev.y * zv.y; s += ev.z * zv.z; s += ev.w * zv.w;
    }
    s += __shfl_xor(s, 1, 64);
    s += __shfl_xor(s, 2, 64);

    float bd = (z_sq[row] - 2.0f * s) + e_sq[n * KCODES + code];
    int   bk = code;
    #pragma unroll
    for (int off = 4; off < 64; off <<= 1) {
      float d2 = __shfl_xor(bd, off, 64);
      int   k2 = __shfl_xor(bk, off, 64);
      if (d2 < bd || (d2 == bd && k2 < bk)) { bd = d2; bk = k2; }
    }
    if (lane == 0)
      atomicMin(&winner[row], ((unsigned long long)__float_as_uint(bd) << 32) | (unsigned)bk);
  }
}

// ------------------------------------------------------------ passB3 (gather)
__global__ __launch_bounds__(256)
void passB3_kernel(const float* __restrict__ z, const float* __restrict__ emb,
                   const unsigned long long* __restrict__ winner, float* __restrict__ out,
                   int* __restrict__ counts, float* __restrict__ lossarr) {
  const int w = threadIdx.x >> 6, lane = threadIdx.x & 63;
  const int gw = blockIdx.x * 4 + w;        // 0..2047
  float lossacc = 0.f;

  for (int i = 0; i < 4; ++i) {
    int row0 = gw * 8 + i * 2;
    int bk0 = (int)(unsigned)winner[row0];
    int bk1 = (int)(unsigned)winner[row0 + 1];
    const float* eb0 = emb + ((size_t)(row0 & 1) * KCODES + bk0) * DSUB;
    const float* eb1 = emb + ((size_t)((row0 + 1) & 1) * KCODES + bk1) * DSUB;
    float4 ev0 = ((const float4*)eb0)[lane];
    float4 ev1 = ((const float4*)eb1)[lane];
    float4 zv0 = ((const float4*)(z + (size_t)row0 * DSUB))[lane];
    float4 zv1 = ((const float4*)(z + (size_t)(row0 + 1) * DSUB))[lane];
    ((float4*)(out + (size_t)row0 * DSUB))[lane] = ev0;
    ((float4*)(out + (size_t)(row0 + 1) * DSUB))[lane] = ev1;
    float dx = zv0.x - ev0.x, dy = zv0.y - ev0.y, dz = zv0.z - ev0.z, dw = zv0.w - ev0.w;
    lossacc += dx * dx + dy * dy + dz * dz + dw * dw;
    dx = zv1.x - ev1.x; dy = zv1.y - ev1.y; dz = zv1.z - ev1.z; dw = zv1.w - ev1.w;
    lossacc += dx * dx + dy * dy + dz * dz + dw * dw;
    if (lane == 0) {
      out[IDX_OFF + row0] = (float)bk0;
      out[IDX_OFF + row0 + 1] = (float)bk1;
      atomicAdd(&counts[(row0 & 1) * KCODES + bk0], 1);
      atomicAdd(&counts[((row0 + 1) & 1) * KCODES + bk1], 1);
    }
  }
  #pragma unroll
  for (int off = 32; off; off >>= 1) lossacc += __shfl_xor(lossacc, off, 64);
  if (lane == 0) lossarr[gw] = lossacc;
}

// ------------------------------------------------------------ final kernel
__global__ void final_kernel(const int* __restrict__ counts, const float* __restrict__ lossarr,
                             float* __restrict__ out) {
  __shared__ float redh[256];
  __shared__ float redl[256];
  float h = 0.0f, ls = 0.0f;
  for (int k = threadIdx.x; k < KCODES; k += 256) {
    float p = (float)(counts[k] + counts[KCODES + k]) * (1.0f / 16384.0f);
    h -= p * logf(p + 1e-10f);
  }
  for (int k = threadIdx.x; k < 2048; k += 256) ls += lossarr[k];
  redh[threadIdx.x] = h;
  redl[threadIdx.x] = ls;
  __syncthreads();
  for (int s = 128; s; s >>= 1) {
    if (threadIdx.x < s) {
      redh[threadIdx.x] += redh[threadIdx.x + s];
      redl[threadIdx.x] += redl[threadIdx.x + s];
    }
    __syncthreads();
  }
  if (threadIdx.x == 0) {
    out[LOSS_OFF + 0] = 0.25f * redl[0] * (1.0f / (float)QUANT_N);
    out[LOSS_OFF + 1] = 0.0f;
    out[LOSS_OFF + 2] = expf(redh[0]);
  }
}

extern "C" void kernel_launch(void* const* d_in, const int* in_sizes, int n_in,
                              void* d_out, int out_size, void* d_ws, size_t ws_size,
                              hipStream_t stream) {
  const float* z   = (const float*)d_in[0];
  const float* emb = (const float*)d_in[1];
  float* out = (float*)d_out;
  char*  ws  = (char*)d_ws;

  float* e_sq   = (float*)(ws + WS_ESQ);
  float* z_sq   = (float*)(ws + WS_ZSQ);
  int*   counts = (int*)(ws + WS_COUNTS);
  unsigned long long* winner = (unsigned long long*)(ws + WS_WINNER);
  float* lossarr = (float*)(ws + WS_LOSSARR);
  unsigned* qtail = (unsigned*)(ws + WS_QTAIL);
  unsigned short* zbf = (unsigned short*)(ws + WS_ZBF);
  unsigned short* ebf = (unsigned short*)(ws + WS_EBF);
  unsigned* queue = (unsigned*)(ws + WS_QUEUE);
  __half* tmbuf = (__half*)(ws + WS_TM);

  prep_kernel<<<1024, 256, 0, stream>>>(z, emb, e_sq, z_sq, zbf, ebf, counts, winner, qtail);
  dim3 gA(32, 16, 2);
  passA_kernel<<<gA, 256, 0, stream>>>(zbf, ebf, e_sq, tmbuf);
  passB1_kernel<<<512, 256, 0, stream>>>(tmbuf, queue, qtail);
  passB2_kernel<<<512, 256, 0, stream>>>(z, emb, e_sq, z_sq, queue, qtail, winner);
  passB3_kernel<<<512, 256, 0, stream>>>(z, emb, winner, out, counts, lossarr);
  final_kernel<<<1, 256, 0, stream>>>(counts, lossarr, out);
}